// Round 10
// baseline (705.811 us; speedup 1.0000x reference)
//
#include <hip/hip_runtime.h>
#include <hip/hip_bf16.h>
#include <stdint.h>

typedef unsigned long long u64;
typedef __attribute__((ext_vector_type(8))) short bf16x8;   // 8 bf16 = 4 VGPRs
typedef __attribute__((ext_vector_type(4))) float f32x4;
typedef __attribute__((ext_vector_type(2))) float f32x2;    // v_pk_*_f32 pair

#define SCOPE_AGENT __HIP_MEMORY_SCOPE_AGENT
#define POISON 0xFFFFFFFFu
#define SPIN_GUARD (1 << 22)   // ~seconds' worth of sleeps; legit waits are <1ms

// hdr word indices (workspace byte 0..255)
#define H_ITEM 0   // dynamic item counter
#define H_PREP 1   // prep_done count (9 when weights ready)
#define H_PLACED 2 // fps blocks that published their CU key
#define H_FDONE 3  // fps blocks finished
#define H_SLEEP 4  // dynamically-parked consumer count (cap 24)

__device__ __forceinline__ unsigned short f2bf(float f) {
    unsigned x = __float_as_uint(f);
    unsigned r = (x + 0x7fffu + ((x >> 16) & 1u)) >> 16;   // RNE
    return (unsigned short)r;
}

// 8 f32 -> bf16x8 via packed RNE converts (v_cvt_pk_bf16_f32).
__device__ __forceinline__ bf16x8 cvt8(float4 a, float4 b) {
    union { bf16x8 v; __hip_bfloat162 h[4]; } u;
    u.h[0] = __float22bfloat162_rn({a.x, a.y});
    u.h[1] = __float22bfloat162_rn({a.z, a.w});
    u.h[2] = __float22bfloat162_rn({b.x, b.y});
    u.h[3] = __float22bfloat162_rn({b.z, b.w});
    return u.v;
}

// 16-lane-group max via 4 DPP steps (xor1/2/4/8 within each row of 16).
__device__ __forceinline__ float group16_max_dpp(float v) {
#define DPP_MAX_STEP(ctrl)                                                     \
    v = fmaxf(v, __int_as_float(__builtin_amdgcn_update_dpp(                   \
               0, __float_as_int(v), (ctrl), 0xf, 0xf, true)))
    DPP_MAX_STEP(0xB1);   // quad_perm xor1
    DPP_MAX_STEP(0x4E);   // quad_perm xor2
    DPP_MAX_STEP(0x141);  // row_half_mirror xor4
    DPP_MAX_STEP(0x140);  // row_mirror xor8
#undef DPP_MAX_STEP
    return v;
}

// LDS-only barrier: skips the vmcnt(0) drain __syncthreads would impose on
// the fire-and-forget newxyz publishes (verified win, R7: -20µs).
__device__ __forceinline__ void lds_barrier() {
    __builtin_amdgcn_sched_barrier(0);
    asm volatile("s_waitcnt lgkmcnt(0)" ::: "memory");
    __builtin_amdgcn_sched_barrier(0);
    __builtin_amdgcn_s_barrier();
    __builtin_amdgcn_sched_barrier(0);
}

// CU identity key: HW_ID bits [15:8] (CU_ID|SH_ID|SE_ID) + XCC_ID.
__device__ __forceinline__ unsigned cu_key() {
    unsigned hw = (unsigned)__builtin_amdgcn_s_getreg(14852) & 0xffu; // HW_ID[15:8]
    unsigned xcc = (unsigned)__builtin_amdgcn_s_getreg(6164) & 0x7u;  // XCC_ID[2:0]
    return (xcc << 8) | hw;   // 0..2047
}

struct WPack { const float* w[9]; const float* b[9]; };

// ---------------------------------------------------------------------------
// FPS producer (blocks 0..7). R7/R9-verified dataflow. Deltas this round
// (both pure dependency-restructurings, bit-identical results):
//  - argmax via a CONTIGUOUS (value,index) binary tree — pairs (2i,2i+1),
//    then (4i,..): every left subtree holds strictly smaller indices, so the
//    >= tie-break reproduces min-index argmax. 4 dependent levels instead of
//    the old 15-deep serial cndmask chain (~-70cy).
//  - wave max: 4 DPP steps (16-lane groups) + 4 readlane + scalar u32 max —
//    bit-exact for non-negative f32 (int order == float order), replacing
//    the 2 high-latency row_bcast DPP steps (~-30cy).
// ---------------------------------------------------------------------------
__device__ __forceinline__ void fps_path(const float* __restrict__ xyz,
                                         float* __restrict__ newxyz,
                                         unsigned* __restrict__ hdr,
                                         unsigned* __restrict__ occ,
                                         unsigned char* smem) {
#pragma clang fp contract(off)
    __builtin_amdgcn_s_setprio(3);
    f32x2* xy = (f32x2*)smem;                 // [4096] x,y pairs (32KB)
    float* zs = (float*)(smem + 32768);       // [4096] z (16KB)
    u64* skey = (u64*)(smem + 49152);         // [2][4]

    const int b = blockIdx.x;
    const int t = threadIdx.x;
    const int lane = t & 63;
    const int wave = t >> 6;

    if (t == 0) {   // publish CU occupancy first thing
        __hip_atomic_store(&occ[cu_key()], 1u, __ATOMIC_RELAXED, SCOPE_AGENT);
        __hip_atomic_fetch_add(&hdr[H_PLACED], 1u, __ATOMIC_RELEASE, SCOPE_AGENT);
    }

    f32x2 px[8], py[8], pz[8], dist[8];
    {
        union { float4 v[12]; float f[48]; } u;
        const float4* src =
            reinterpret_cast<const float4*>(xyz + (size_t)b * 12288) + t * 12;
#pragma unroll
        for (int w = 0; w < 12; ++w) u.v[w] = src[w];
#pragma unroll
        for (int i = 0; i < 8; ++i) {
            px[i] = (f32x2){u.f[6 * i + 0], u.f[6 * i + 3]};
            py[i] = (f32x2){u.f[6 * i + 1], u.f[6 * i + 4]};
            pz[i] = (f32x2){u.f[6 * i + 2], u.f[6 * i + 5]};
            dist[i] = (f32x2){1e10f, 1e10f};
            const int j = t * 16 + 2 * i;
            xy[j] = (f32x2){px[i].x, py[i].x};
            xy[j + 1] = (f32x2){px[i].y, py[i].y};
            zs[j] = pz[i].x; zs[j + 1] = pz[i].y;
        }
    }
    __syncthreads();   // staging barrier: full semantics, once

    int far = 0;
    for (int k = 0; k < 1024; ++k) {
        const f32x2 cc = xy[far];             // b64 broadcast
        const float cx = cc.x, cy = cc.y;
        const float cz = zs[far];             // b32 broadcast (overlapped)
        if (t == 0) {   // fire-and-forget; words self-validate vs poison
            const size_t o = ((size_t)b * 1024 + k) * 3;
            __hip_atomic_store(&newxyz[o + 0], cx, __ATOMIC_RELAXED, SCOPE_AGENT);
            __hip_atomic_store(&newxyz[o + 1], cy, __ATOMIC_RELAXED, SCOPE_AGENT);
            __hip_atomic_store(&newxyz[o + 2], cz, __ATOMIC_RELAXED, SCOPE_AGENT);
        }
        const f32x2 c2x = (f32x2){cx, cx};
        const f32x2 c2y = (f32x2){cy, cy};
        const f32x2 c2z = (f32x2){cz, cz};
#pragma unroll
        for (int i = 0; i < 8; ++i) {
            const f32x2 dx = px[i] - c2x;
            const f32x2 dy = py[i] - c2y;
            const f32x2 dz = pz[i] - c2z;
            const f32x2 s = dx * dx + dy * dy;   // pk_mul + pk_add (no fma)
            const f32x2 d = s + dz * dz;
            dist[i].x = fminf(dist[i].x, d.x);
            dist[i].y = fminf(dist[i].y, d.y);
        }
        float dv[16];
#pragma unroll
        for (int i = 0; i < 8; ++i) { dv[2 * i] = dist[i].x; dv[2 * i + 1] = dist[i].y; }

        // contiguous (value,index) argmax tree, min-index tie-break
        float v8[8]; int j8[8];
#pragma unroll
        for (int i = 0; i < 8; ++i) {
            const bool sel = dv[2 * i] >= dv[2 * i + 1];
            v8[i] = sel ? dv[2 * i] : dv[2 * i + 1];
            j8[i] = sel ? 2 * i : 2 * i + 1;
        }
        float v4a[4]; int j4a[4];
#pragma unroll
        for (int i = 0; i < 4; ++i) {
            const bool sel = v8[2 * i] >= v8[2 * i + 1];
            v4a[i] = sel ? v8[2 * i] : v8[2 * i + 1];
            j4a[i] = sel ? j8[2 * i] : j8[2 * i + 1];
        }
        float v2a[2]; int j2a[2];
#pragma unroll
        for (int i = 0; i < 2; ++i) {
            const bool sel = v4a[2 * i] >= v4a[2 * i + 1];
            v2a[i] = sel ? v4a[2 * i] : v4a[2 * i + 1];
            j2a[i] = sel ? j4a[2 * i] : j4a[2 * i + 1];
        }
        const bool selt = v2a[0] >= v2a[1];
        const float bv = selt ? v2a[0] : v2a[1];
        const int bj = selt ? j2a[0] : j2a[1];
        const int myidx = t * 16 + bj;

        // wave max: 4-step DPP (16-lane groups) + readlane + scalar u32 max
        const float g16 = group16_max_dpp(bv);
        const int gb = __float_as_int(g16);
        const unsigned q0 = (unsigned)__builtin_amdgcn_readlane(gb, 0);
        const unsigned q1 = (unsigned)__builtin_amdgcn_readlane(gb, 16);
        const unsigned q2 = (unsigned)__builtin_amdgcn_readlane(gb, 32);
        const unsigned q3 = (unsigned)__builtin_amdgcn_readlane(gb, 48);
        const unsigned w01 = q0 > q1 ? q0 : q1;
        const unsigned w23 = q2 > q3 ? q2 : q3;
        const unsigned wbits = w01 > w23 ? w01 : w23;   // == bits of wave max

        const u64 mask = __ballot(__float_as_uint(bv) == wbits);
        const int fl = (int)__builtin_ctzll(mask);
        const int widx = __builtin_amdgcn_readlane(myidx, fl);

        const int pp = k & 1;
        if (lane == 0)
            skey[pp * 4 + wave] =
                ((u64)wbits << 32) | (unsigned)(4095 - widx);
        lds_barrier();   // LDS-only ordering: no vmcnt drain of the publishes
        const ulonglong2 ka = *reinterpret_cast<const ulonglong2*>(&skey[pp * 4 + 0]);
        const ulonglong2 kb = *reinterpret_cast<const ulonglong2*>(&skey[pp * 4 + 2]);
        const u64 m01 = (ka.x > ka.y) ? ka.x : ka.y;
        const u64 m23 = (kb.x > kb.y) ? kb.x : kb.y;
        const u64 mm = (m01 > m23) ? m01 : m23;
        far = 4095 - (int)(unsigned)(mm & 0xffffffffull);
    }
    if (t == 0)
        __hip_atomic_fetch_add(&hdr[H_FDONE], 1u, __ATOMIC_RELEASE, SCOPE_AGENT);
}

// ---------------------------------------------------------------------------
// Weight prep (blocks 8..16): transpose 9 f32 [k][n] weights to bf16 [n][SW]
// zero-padded MFMA-B layout + f32 biases. Release-RMW publishes them.
// ---------------------------------------------------------------------------
__device__ __forceinline__ void prep_path(const WPack& p,
                                          unsigned short* __restrict__ wout,
                                          float* __restrict__ bout,
                                          unsigned* __restrict__ hdr) {
    constexpr int cin[9]  = {67, 32, 32,  67, 64, 64,  67, 64, 96};
    constexpr int cout[9] = {32, 32, 64,  64, 64, 128, 64, 96, 128};
    constexpr int sw[9]   = {104, 40, 40, 104, 72, 72, 104, 72, 104};
    constexpr int woff[9] = {0, 3328, 4608, 7168, 13824, 18432, 27648, 34304, 41216};
    constexpr int boff[9] = {0, 32, 64, 128, 192, 256, 384, 448, 544};
    const int L = blockIdx.x - 8;
    const float* w = p.w[L];
    const int ci = cin[L], co = cout[L], s = sw[L];
    unsigned short* dst = wout + woff[L];
    for (int e = threadIdx.x; e < co * s; e += 256) {
        const int n = e / s, k = e % s;
        dst[e] = (k < ci) ? f2bf(w[(size_t)k * co + n]) : (unsigned short)0;
    }
    for (int e = threadIdx.x; e < co; e += 256) bout[boff[L] + e] = p.b[L][e];
    __syncthreads();
    if (threadIdx.x == 0)
        __hip_atomic_fetch_add(&hdr[H_PREP], 1u, __ATOMIC_RELEASE, SCOPE_AGENT);
}

// Poll one group's centroid words until non-poison (lane0), broadcast to wave.
__device__ __forceinline__ void poll_centroid(const float* __restrict__ newxyz,
                                              int g, int lane,
                                              float& ncx, float& ncy, float& ncz) {
    const unsigned* ncw = (const unsigned*)(newxyz + (size_t)g * 3);
    unsigned w0 = 0, w1 = 0, w2 = 0;
    if (lane == 0) {
        int n = 0;
        for (;;) {
            w0 = __hip_atomic_load(&ncw[0], __ATOMIC_RELAXED, SCOPE_AGENT);
            w1 = __hip_atomic_load(&ncw[1], __ATOMIC_RELAXED, SCOPE_AGENT);
            w2 = __hip_atomic_load(&ncw[2], __ATOMIC_RELAXED, SCOPE_AGENT);
            if (w0 != POISON && w1 != POISON && w2 != POISON) break;
            if (++n > SPIN_GUARD) break;                 // watchdog
            if (n < 64) __builtin_amdgcn_s_sleep(8);
            else        __builtin_amdgcn_s_sleep(32);
        }
    }
    ncx = __uint_as_float((unsigned)__builtin_amdgcn_readfirstlane((int)w0));
    ncy = __uint_as_float((unsigned)__builtin_amdgcn_readfirstlane((int)w1));
    ncz = __uint_as_float((unsigned)__builtin_amdgcn_readfirstlane((int)w2));
}

// ---------------------------------------------------------------------------
// Single-radius ball query for one group, one wave.
// ---------------------------------------------------------------------------
template <int NS>
__device__ __forceinline__ void ballq1(const float* __restrict__ base,
                                       float cx, float cy, float cz, float r2,
                                       unsigned short* __restrict__ out, int lane) {
    int cnt = 0, first = 0;
    const u64 lower = (((u64)1) << lane) - 1;
    for (int it = 0; it < 64; ++it) {
        const int j = it * 64 + lane;
        const float* pp = base + j * 3;
        const float dx = pp[0] - cx;
        const float dy = pp[1] - cy;
        const float dz = pp[2] - cz;
        const float d2 = __fadd_rn(__fadd_rn(__fmul_rn(dx, dx), __fmul_rn(dy, dy)),
                                   __fmul_rn(dz, dz));
        const bool in = d2 < r2;
        const u64 m = __ballot(in);
        if (cnt == 0 && m) first = it * 64 + (int)__builtin_ctzll(m);
        const int pos = cnt + (int)__builtin_popcountll(m & lower);
        if (in && pos < NS) out[pos] = (unsigned short)j;
        cnt += (int)__builtin_popcountll(m);
        if (cnt >= NS) break;
    }
    for (int pos = cnt + lane; pos < NS; pos += 64) out[pos] = (unsigned short)first;
}

// ---------------------------------------------------------------------------
// Layer 1, A-fragments DIRECT from global points (no LDS staging, no gather).
// ---------------------------------------------------------------------------
template <int MW, int Cout, int SOUT>
__device__ __forceinline__ void layer1_direct(
    const float* __restrict__ pts,        // points + bb*4096*64
    const float* __restrict__ xyzb,       // xyz + bb*12288
    const unsigned short* __restrict__ idxb,  // LDS, rows for this tile
    float ncx, float ncy, float ncz,
    const unsigned short* __restrict__ Wg, const float* __restrict__ bg,
    unsigned short* __restrict__ dst, int lane, int mslice) {
    constexpr int SW = 104;
    constexpr int MT = MW / 16;
    constexpr int NT = Cout / 16;
    const int ml = lane & 15;
    const int quad = lane >> 4;

    bf16x8 afr[MT][3];
#pragma unroll
    for (int mt = 0; mt < MT; ++mt) {
        const int row = mslice * MW + mt * 16 + ml;
        const int id = idxb[row] & 4095;
        const float* rb = pts + ((size_t)id << 6) + quad * 8;
        const float4* r4 = reinterpret_cast<const float4*>(rb);
        afr[mt][0] = cvt8(r4[0], r4[1]);
        const float4* r4b = reinterpret_cast<const float4*>(rb + 32);
        afr[mt][1] = cvt8(r4b[0], r4b[1]);
        union { bf16x8 v; unsigned short h[8]; } tg;
        tg.v = (bf16x8)(short)0;
        if (quad == 0) {
            const float* pz = xyzb + (size_t)id * 3;
            tg.h[0] = f2bf(pz[0] - ncx);
            tg.h[1] = f2bf(pz[1] - ncy);
            tg.h[2] = f2bf(pz[2] - ncz);
        }
        afr[mt][2] = tg.v;
    }

    f32x4 acc[MT][NT];
#pragma unroll
    for (int mt = 0; mt < MT; ++mt)
#pragma unroll
        for (int nt = 0; nt < NT; ++nt) acc[mt][nt] = (f32x4){0.f, 0.f, 0.f, 0.f};

#pragma unroll
    for (int ks = 0; ks < 3; ++ks) {
        bf16x8 bfr[NT];
#pragma unroll
        for (int nt = 0; nt < NT; ++nt)
            bfr[nt] = *reinterpret_cast<const bf16x8*>(
                Wg + (nt * 16 + ml) * SW + ks * 32 + quad * 8);
#pragma unroll
        for (int mt = 0; mt < MT; ++mt)
#pragma unroll
            for (int nt = 0; nt < NT; ++nt)
                acc[mt][nt] = __builtin_amdgcn_mfma_f32_16x16x32_bf16(
                    afr[mt][ks], bfr[nt], acc[mt][nt], 0, 0, 0);
    }

#pragma unroll
    for (int nt = 0; nt < NT; ++nt) {
        const int col = nt * 16 + ml;
        const float bv = bg[col];
#pragma unroll
        for (int mt = 0; mt < MT; ++mt)
#pragma unroll
            for (int r = 0; r < 4; ++r) {
                const float v = fmaxf(acc[mt][nt][r] + bv, 0.0f);
                dst[(mslice * MW + mt * 16 + quad * 4 + r) * SOUT + col] = f2bf(v);
            }
    }
}

// Middle layer: A from LDS, B from prepped global; relu+store bf16 to LDS.
template <int MW, int Kp, int Cout, int SIN>
__device__ __forceinline__ void layer_mid(const unsigned short* __restrict__ src,
                                          unsigned short* __restrict__ dst,
                                          const unsigned short* __restrict__ Wg,
                                          const float* __restrict__ bg,
                                          int lane, int mslice) {
    constexpr int MT = MW / 16;
    constexpr int NT = Cout / 16;
    constexpr int SOUT = Cout + 8;
    const int ml = lane & 15;
    const int quad = lane >> 4;

    f32x4 acc[MT][NT];
#pragma unroll
    for (int mt = 0; mt < MT; ++mt)
#pragma unroll
        for (int nt = 0; nt < NT; ++nt) acc[mt][nt] = (f32x4){0.f, 0.f, 0.f, 0.f};

#pragma unroll
    for (int ks = 0; ks < Kp; ks += 32) {
        bf16x8 afr[MT], bfr[NT];
#pragma unroll
        for (int mt = 0; mt < MT; ++mt)
            afr[mt] = *reinterpret_cast<const bf16x8*>(
                src + (mslice * MW + mt * 16 + ml) * SIN + ks + quad * 8);
#pragma unroll
        for (int nt = 0; nt < NT; ++nt)
            bfr[nt] = *reinterpret_cast<const bf16x8*>(
                Wg + (nt * 16 + ml) * SIN + ks + quad * 8);
#pragma unroll
        for (int mt = 0; mt < MT; ++mt)
#pragma unroll
            for (int nt = 0; nt < NT; ++nt)
                acc[mt][nt] = __builtin_amdgcn_mfma_f32_16x16x32_bf16(
                    afr[mt], bfr[nt], acc[mt][nt], 0, 0, 0);
    }

#pragma unroll
    for (int nt = 0; nt < NT; ++nt) {
        const int col = nt * 16 + ml;
        const float bv = bg[col];
#pragma unroll
        for (int mt = 0; mt < MT; ++mt)
#pragma unroll
            for (int r = 0; r < 4; ++r) {
                const float v = fmaxf(acc[mt][nt][r] + bv, 0.0f);
                dst[(mslice * MW + mt * 16 + quad * 4 + r) * SOUT + col] = f2bf(v);
            }
    }
}

// Last layer + maxpool. DIRECT: single wave owns the whole group -> write the
// col max straight to global. Else (4-wave tile) atomicMax into LDS Mx.
template <int MW, int Kp, int Cout, int SIN, bool DIRECT>
__device__ __forceinline__ void layer_last(const unsigned short* __restrict__ src,
                                           const unsigned short* __restrict__ Wg,
                                           const float* __restrict__ bg,
                                           float* __restrict__ out,
                                           int lane, int mslice) {
    constexpr int MT = MW / 16;
    constexpr int NT = Cout / 16;
    const int ml = lane & 15;
    const int quad = lane >> 4;

    f32x4 acc[MT][NT];
#pragma unroll
    for (int mt = 0; mt < MT; ++mt)
#pragma unroll
        for (int nt = 0; nt < NT; ++nt) acc[mt][nt] = (f32x4){0.f, 0.f, 0.f, 0.f};

#pragma unroll
    for (int ks = 0; ks < Kp; ks += 32) {
        bf16x8 afr[MT], bfr[NT];
#pragma unroll
        for (int mt = 0; mt < MT; ++mt)
            afr[mt] = *reinterpret_cast<const bf16x8*>(
                src + (mslice * MW + mt * 16 + ml) * SIN + ks + quad * 8);
#pragma unroll
        for (int nt = 0; nt < NT; ++nt)
            bfr[nt] = *reinterpret_cast<const bf16x8*>(
                Wg + (nt * 16 + ml) * SIN + ks + quad * 8);
#pragma unroll
        for (int mt = 0; mt < MT; ++mt)
#pragma unroll
            for (int nt = 0; nt < NT; ++nt)
                acc[mt][nt] = __builtin_amdgcn_mfma_f32_16x16x32_bf16(
                    afr[mt], bfr[nt], acc[mt][nt], 0, 0, 0);
    }

#pragma unroll
    for (int nt = 0; nt < NT; ++nt) {
        const int col = nt * 16 + ml;
        const float bv = bg[col];
        float mx = 0.0f;   // relu floor folds into the max
#pragma unroll
        for (int mt = 0; mt < MT; ++mt)
#pragma unroll
            for (int r = 0; r < 4; ++r) mx = fmaxf(mx, acc[mt][nt][r] + bv);
        mx = fmaxf(mx, __shfl_xor(mx, 16, 64));
        mx = fmaxf(mx, __shfl_xor(mx, 32, 64));
        if (quad == 0) {
            if constexpr (DIRECT) out[col] = mx;
            else atomicMax(reinterpret_cast<int*>(out + col), __float_as_int(mx));
        }
    }
}

// Branch 1/2: 4 groups per item, one wave per group, fully wave-independent.
template <int NS, int C1, int C2, int C3, int CH_OFF>
__device__ __forceinline__ void consume_small(
    unsigned char* smem, const float* __restrict__ xyz,
    const float* __restrict__ points, const float* __restrict__ newxyz,
    const unsigned short* wg1, const unsigned short* wg2, const unsigned short* wg3,
    const float* bg1, const float* bg2, const float* bg3,
    float* __restrict__ outfeat, int gbase, int bb, float r2) {
    constexpr int SB = C1 + 8, SC = C2 + 8;
    unsigned short* Bb = (unsigned short*)smem;        // [4][NS][SB]
    unsigned short* Cb = Bb + 4 * NS * SB;             // [4][NS][SC]
    unsigned short* idxb = Cb + 4 * NS * SC;           // [4][NS]
    const int lane = threadIdx.x & 63;
    const int wave = threadIdx.x >> 6;
    const int g = gbase + wave;
    float ncx, ncy, ncz;
    poll_centroid(newxyz, g, lane, ncx, ncy, ncz);
    const float* xb = xyz + (size_t)bb * 12288;
    unsigned short* idxw = idxb + wave * NS;
    ballq1<NS>(xb, ncx, ncy, ncz, r2, idxw, lane);
    layer1_direct<NS, C1, SB>(points + ((size_t)bb << 18), xb, idxw, ncx, ncy, ncz,
                              wg1, bg1, Bb + wave * NS * SB, lane, 0);
    layer_mid<NS, C1, C2, SB>(Bb + wave * NS * SB, Cb + wave * NS * SC, wg2, bg2,
                              lane, 0);
    layer_last<NS, C2, C3, SC, true>(Cb + wave * NS * SC, wg3, bg3,
                                     outfeat + (size_t)g * 320 + CH_OFF, lane, 0);
}

// Branch 3: one 128-sample group per item, 4 waves (32 rows each).
__device__ __forceinline__ void consume_b3(
    unsigned char* smem, const float* __restrict__ xyz,
    const float* __restrict__ points, const float* __restrict__ newxyz,
    const unsigned short* wg1, const unsigned short* wg2, const unsigned short* wg3,
    const float* bg1, const float* bg2, const float* bg3,
    float* __restrict__ outfeat, int g, int bb) {
    constexpr int SB = 72, SC = 104;
    unsigned short* Bb = (unsigned short*)smem;        // [128][72]
    unsigned short* Cb = Bb + 128 * SB;                // [128][104]
    float* Mx = (float*)(Cb + 128 * SC);               // [128]
    unsigned short* idxb = (unsigned short*)(Mx + 128);// [128]
    float* mail = (float*)(idxb + 128);                // [3] centroid
    const int tid = threadIdx.x;
    const int lane = tid & 63;
    const int wave = tid >> 6;
    const float* xb = xyz + (size_t)bb * 12288;
    float ncx, ncy, ncz;
    if (wave == 0) {
        poll_centroid(newxyz, g, lane, ncx, ncy, ncz);
        if (lane == 0) { mail[0] = ncx; mail[1] = ncy; mail[2] = ncz; }
        ballq1<128>(xb, ncx, ncy, ncz, 0.16f, idxb, lane);
    }
    if (tid >= 128) Mx[tid - 128] = 0.0f;
    __syncthreads();
    if (wave != 0) { ncx = mail[0]; ncy = mail[1]; ncz = mail[2]; }
    layer1_direct<32, 64, SB>(points + ((size_t)bb << 18), xb, idxb, ncx, ncy, ncz,
                              wg1, bg1, Bb, lane, wave);
    layer_mid<32, 64, 96, SB>(Bb, Cb, wg2, bg2, lane, wave);
    layer_last<32, 96, 128, SC, false>(Cb, wg3, bg3, Mx, lane, wave);
    __syncthreads();
    if (tid < 128) outfeat[(size_t)g * 320 + 192 + tid] = Mx[tid];
}

// ---------------------------------------------------------------------------
// Mega kernel (R7 structure). Grid 768 = 256 CU x 3 blocks, all co-resident.
// Blocks 0..7 FPS; 8..16 prep then consume; rest consume. Consumers on an
// FPS CU park until FPS done (static bx%256<8 + dynamic HW_ID, cap 24).
// Work dynamically assigned in deadline order: 256 chunks x {8 b1, 8 b2,
// 32 b3} = 12288 items. All waits SPIN_GUARDed.
// ---------------------------------------------------------------------------
__global__ __launch_bounds__(256, 3) void mega_kernel(
    const float* __restrict__ xyz, const float* __restrict__ points, WPack p,
    float* __restrict__ newxyz, float* __restrict__ outfeat,
    unsigned* __restrict__ hdr, unsigned* __restrict__ occ,
    unsigned short* __restrict__ wprep, float* __restrict__ bprep) {
    __shared__ __align__(16) unsigned char smem[49408];
    __shared__ int itemLDS[2];
    const int bx = blockIdx.x;
    if (bx < 8) { fps_path(xyz, newxyz, hdr, occ, smem); return; }
    if (bx < 17) prep_path(p, wprep, bprep, hdr);

    if (threadIdx.x == 0) {
        int n = 0;
        while (__hip_atomic_load(&hdr[H_PLACED], __ATOMIC_RELAXED, SCOPE_AGENT) < 8u &&
               ++n < SPIN_GUARD)
            __builtin_amdgcn_s_sleep(2);
        (void)__hip_atomic_load(&hdr[H_PLACED], __ATOMIC_ACQUIRE, SCOPE_AGENT);
        bool doze = (bx >= 17) && ((bx & 255) < 8);
        if (!doze &&
            __hip_atomic_load(&occ[cu_key()], __ATOMIC_RELAXED, SCOPE_AGENT)) {
            const unsigned prev = __hip_atomic_fetch_add(&hdr[H_SLEEP], 1u,
                                                         __ATOMIC_RELAXED, SCOPE_AGENT);
            doze = (prev < 24u);
        }
        n = 0;
        if (doze)
            while (__hip_atomic_load(&hdr[H_FDONE], __ATOMIC_RELAXED, SCOPE_AGENT) < 8u &&
                   ++n < SPIN_GUARD)
                __builtin_amdgcn_s_sleep(127);
        n = 0;
        while (__hip_atomic_load(&hdr[H_PREP], __ATOMIC_RELAXED, SCOPE_AGENT) < 9u &&
               ++n < SPIN_GUARD)
            __builtin_amdgcn_s_sleep(8);
        (void)__hip_atomic_load(&hdr[H_PREP], __ATOMIC_ACQUIRE, SCOPE_AGENT);
    }

    for (int slot = 0;; slot ^= 1) {
        if (threadIdx.x == 0)
            itemLDS[slot] = (int)__hip_atomic_fetch_add(&hdr[H_ITEM], 1u,
                                                        __ATOMIC_RELAXED, SCOPE_AGENT);
        __syncthreads();   // publishes item; doubles as inter-item LDS barrier
        const int item = itemLDS[slot];
        if (item >= 12288) break;

        const int chunk = item / 48;
        const int r = item - chunk * 48;
        int bb, br, soff = 0;
        if (r < 8)       { br = 0; bb = r; }
        else if (r < 16) { br = 1; bb = r - 8; }
        else             { br = 2; bb = (r - 16) & 7; soff = (r - 16) >> 3; }
        const int gbase = bb * 1024 + chunk * 4;
        if (br == 0)
            consume_small<16, 32, 32, 64, 0>(smem, xyz, points, newxyz,
                wprep + 0, wprep + 3328, wprep + 4608,
                bprep + 0, bprep + 32, bprep + 64, outfeat, gbase, bb, 0.01f);
        else if (br == 1)
            consume_small<32, 64, 64, 128, 64>(smem, xyz, points, newxyz,
                wprep + 7168, wprep + 13824, wprep + 18432,
                bprep + 128, bprep + 192, bprep + 256, outfeat, gbase, bb, 0.04f);
        else
            consume_b3(smem, xyz, points, newxyz,
                wprep + 27648, wprep + 34304, wprep + 41216,
                bprep + 384, bprep + 448, bprep + 544, outfeat, gbase + soff, bb);
    }
}

// ---------------------------------------------------------------------------
extern "C" void kernel_launch(void* const* d_in, const int* in_sizes, int n_in,
                              void* d_out, int out_size, void* d_ws, size_t ws_size,
                              hipStream_t stream) {
    (void)in_sizes; (void)n_in; (void)out_size; (void)ws_size;
    const float* xyz = (const float*)d_in[0];
    const float* points = (const float*)d_in[1];
    WPack pack;
    int p = 2;
    for (int L = 0; L < 9; ++L) {
        pack.w[L] = (const float*)d_in[p++];
        pack.b[L] = (const float*)d_in[p++];
    }
    float* newxyz = (float*)d_out;                  // 8*1024*3
    float* outfeat = (float*)d_out + 8 * 1024 * 3;  // 8*1024*320

    // ws layout: [0,256) hdr, [256,8448) occupancy map (2048 u32),
    // [8448, +109056) prepped bf16 weights, then f32 biases.
    unsigned* hdr = (unsigned*)d_ws;
    unsigned* occ = (unsigned*)((char*)d_ws + 256);
    unsigned short* wprep = (unsigned short*)((char*)d_ws + 8448);
    float* bprep = (float*)((char*)d_ws + 8448 + 109056);

    (void)hipMemsetAsync(d_ws, 0, 8448, stream);              // counters + CU map
    (void)hipMemsetAsync(newxyz, 0xFF, 8 * 1024 * 3 * 4, stream);  // poison centroids
    mega_kernel<<<dim3(768), dim3(256), 0, stream>>>(
        xyz, points, pack, newxyz, outfeat, hdr, occ, wprep, bprep);
}

// Round 11
// 644.151 us; speedup vs baseline: 1.0957x; 1.0957x over previous
//
#include <hip/hip_runtime.h>
#include <hip/hip_bf16.h>
#include <stdint.h>

typedef unsigned long long u64;
typedef __attribute__((ext_vector_type(8))) short bf16x8;   // 8 bf16 = 4 VGPRs
typedef __attribute__((ext_vector_type(4))) float f32x4;
typedef __attribute__((ext_vector_type(2))) float f32x2;    // v_pk_*_f32 pair

#define SCOPE_AGENT __HIP_MEMORY_SCOPE_AGENT
#define POISON 0xFFFFFFFFu
#define SPIN_GUARD (1 << 22)   // ~seconds' worth of sleeps; legit waits are <1ms

// hdr word indices (workspace byte 0..255)
#define H_ITEM 0   // dynamic item counter
#define H_PREP 1   // prep_done count (9 when weights ready)
#define H_PLACED 2 // fps blocks that published their CU key
#define H_FDONE 3  // fps blocks finished
#define H_SLEEP 4  // dynamically-parked consumer count (cap 24)

__device__ __forceinline__ unsigned short f2bf(float f) {
    unsigned x = __float_as_uint(f);
    unsigned r = (x + 0x7fffu + ((x >> 16) & 1u)) >> 16;   // RNE
    return (unsigned short)r;
}

// 8 f32 -> bf16x8 via packed RNE converts (v_cvt_pk_bf16_f32).
__device__ __forceinline__ bf16x8 cvt8(float4 a, float4 b) {
    union { bf16x8 v; __hip_bfloat162 h[4]; } u;
    u.h[0] = __float22bfloat162_rn({a.x, a.y});
    u.h[1] = __float22bfloat162_rn({a.z, a.w});
    u.h[2] = __float22bfloat162_rn({b.x, b.y});
    u.h[3] = __float22bfloat162_rn({b.z, b.w});
    return u.v;
}

// Wave64 max-reduce of a non-negative f32 at VALU speed (DPP, no LDS hops).
__device__ __forceinline__ float wave_max_dpp(float v) {
#define DPP_MAX_STEP(ctrl)                                                     \
    v = fmaxf(v, __int_as_float(__builtin_amdgcn_update_dpp(                   \
               0, __float_as_int(v), (ctrl), 0xf, 0xf, true)))
    DPP_MAX_STEP(0xB1);   // quad_perm xor1
    DPP_MAX_STEP(0x4E);   // quad_perm xor2
    DPP_MAX_STEP(0x141);  // row_half_mirror xor4
    DPP_MAX_STEP(0x140);  // row_mirror xor8
    DPP_MAX_STEP(0x142);  // row_bcast15
    DPP_MAX_STEP(0x143);  // row_bcast31
#undef DPP_MAX_STEP
    return __int_as_float(__builtin_amdgcn_readlane(__float_as_int(v), 63));
}

// LDS-only barrier: skips the vmcnt(0) drain __syncthreads would impose on
// the fire-and-forget newxyz publishes (verified win, R7: -20µs).
__device__ __forceinline__ void lds_barrier() {
    __builtin_amdgcn_sched_barrier(0);
    asm volatile("s_waitcnt lgkmcnt(0)" ::: "memory");
    __builtin_amdgcn_sched_barrier(0);
    __builtin_amdgcn_s_barrier();
    __builtin_amdgcn_sched_barrier(0);
}

// CU identity key: HW_ID bits [15:8] (CU_ID|SH_ID|SE_ID) + XCC_ID.
__device__ __forceinline__ unsigned cu_key() {
    unsigned hw = (unsigned)__builtin_amdgcn_s_getreg(14852) & 0xffu; // HW_ID[15:8]
    unsigned xcc = (unsigned)__builtin_amdgcn_s_getreg(6164) & 0x7u;  // XCC_ID[2:0]
    return (xcc << 8) | hw;   // 0..2047
}

struct WPack { const float* w[9]; const float* b[9]; };

// ---------------------------------------------------------------------------
// FPS producer (blocks 0..7). Best-measured configuration (R7: 572µs disp):
// 4 waves x 16 pts/lane, xs/ys/zs LDS staging, one dependent broadcast read
// per iteration, serial cndmask argmax (min-index ties), 6-step DPP wave max,
// double-buffered skey mailbox, lds_barrier in-loop, fire-and-forget
// agent-coherent publishes of self-validating words (consumers poll vs
// poison). Probed alternatives that regressed: mailbox-coords (-100µs),
// 8-wave reshape (-220µs), argmax tree + readlane max (-56µs); f32x2
// coord packing was null. This is the serial-chain local optimum.
// ---------------------------------------------------------------------------
__device__ __forceinline__ void fps_path(const float* __restrict__ xyz,
                                         float* __restrict__ newxyz,
                                         unsigned* __restrict__ hdr,
                                         unsigned* __restrict__ occ,
                                         unsigned char* smem) {
#pragma clang fp contract(off)
    __builtin_amdgcn_s_setprio(3);
    float* xs = (float*)smem;
    float* ys = xs + 4096;
    float* zs = ys + 4096;
    u64* skey = (u64*)(smem + 49152);   // [2][4]

    const int b = blockIdx.x;
    const int t = threadIdx.x;
    const int lane = t & 63;
    const int wave = t >> 6;

    if (t == 0) {   // publish CU occupancy first thing
        __hip_atomic_store(&occ[cu_key()], 1u, __ATOMIC_RELAXED, SCOPE_AGENT);
        __hip_atomic_fetch_add(&hdr[H_PLACED], 1u, __ATOMIC_RELEASE, SCOPE_AGENT);
    }

    f32x2 px[8], py[8], pz[8], dist[8];
    {
        union { float4 v[12]; float f[48]; } u;
        const float4* src =
            reinterpret_cast<const float4*>(xyz + (size_t)b * 12288) + t * 12;
#pragma unroll
        for (int w = 0; w < 12; ++w) u.v[w] = src[w];
#pragma unroll
        for (int i = 0; i < 8; ++i) {
            px[i] = (f32x2){u.f[6 * i + 0], u.f[6 * i + 3]};
            py[i] = (f32x2){u.f[6 * i + 1], u.f[6 * i + 4]};
            pz[i] = (f32x2){u.f[6 * i + 2], u.f[6 * i + 5]};
            dist[i] = (f32x2){1e10f, 1e10f};
            const int j = t * 16 + 2 * i;
            xs[j] = px[i].x; xs[j + 1] = px[i].y;
            ys[j] = py[i].x; ys[j + 1] = py[i].y;
            zs[j] = pz[i].x; zs[j + 1] = pz[i].y;
        }
    }
    __syncthreads();   // staging barrier: full semantics, once

    int far = 0;
    for (int k = 0; k < 1024; ++k) {
        const float cx = xs[far], cy = ys[far], cz = zs[far];
        if (t == 0) {   // fire-and-forget; words self-validate vs poison
            const size_t o = ((size_t)b * 1024 + k) * 3;
            __hip_atomic_store(&newxyz[o + 0], cx, __ATOMIC_RELAXED, SCOPE_AGENT);
            __hip_atomic_store(&newxyz[o + 1], cy, __ATOMIC_RELAXED, SCOPE_AGENT);
            __hip_atomic_store(&newxyz[o + 2], cz, __ATOMIC_RELAXED, SCOPE_AGENT);
        }
        const f32x2 c2x = (f32x2){cx, cx};
        const f32x2 c2y = (f32x2){cy, cy};
        const f32x2 c2z = (f32x2){cz, cz};
#pragma unroll
        for (int i = 0; i < 8; ++i) {
            const f32x2 dx = px[i] - c2x;
            const f32x2 dy = py[i] - c2y;
            const f32x2 dz = pz[i] - c2z;
            const f32x2 s = dx * dx + dy * dy;   // pk_mul + pk_add (no fma)
            const f32x2 d = s + dz * dz;
            dist[i].x = fminf(dist[i].x, d.x);
            dist[i].y = fminf(dist[i].y, d.y);
        }
        float dv[16];
#pragma unroll
        for (int i = 0; i < 8; ++i) { dv[2 * i] = dist[i].x; dv[2 * i + 1] = dist[i].y; }
        float m8[8], m4[4], bv;
#pragma unroll
        for (int i = 0; i < 8; ++i) m8[i] = fmaxf(dv[i], dv[i + 8]);
#pragma unroll
        for (int i = 0; i < 4; ++i) m4[i] = fmaxf(m8[i], m8[i + 4]);
        bv = fmaxf(fmaxf(m4[0], m4[1]), fmaxf(m4[2], m4[3]));
        int bj = 15;
#pragma unroll
        for (int i = 14; i >= 0; --i) bj = (dv[i] == bv) ? i : bj;
        const int myidx = t * 16 + bj;

        const float wmax = wave_max_dpp(bv);
        const u64 mask = __ballot(bv == wmax);
        const int fl = (int)__builtin_ctzll(mask);
        const int widx = __builtin_amdgcn_readlane(myidx, fl);

        const int pp = k & 1;
        if (lane == 0)
            skey[pp * 4 + wave] =
                ((u64)__float_as_uint(wmax) << 32) | (unsigned)(4095 - widx);
        lds_barrier();   // LDS-only ordering: no vmcnt drain of the publishes
        const ulonglong2 ka = *reinterpret_cast<const ulonglong2*>(&skey[pp * 4 + 0]);
        const ulonglong2 kb = *reinterpret_cast<const ulonglong2*>(&skey[pp * 4 + 2]);
        const u64 m01 = (ka.x > ka.y) ? ka.x : ka.y;
        const u64 m23 = (kb.x > kb.y) ? kb.x : kb.y;
        const u64 mm = (m01 > m23) ? m01 : m23;
        far = 4095 - (int)(unsigned)(mm & 0xffffffffull);
    }
    if (t == 0)
        __hip_atomic_fetch_add(&hdr[H_FDONE], 1u, __ATOMIC_RELEASE, SCOPE_AGENT);
}

// ---------------------------------------------------------------------------
// Weight prep (blocks 8..16): transpose 9 f32 [k][n] weights to bf16 [n][SW]
// zero-padded MFMA-B layout + f32 biases. Release-RMW publishes them.
// ---------------------------------------------------------------------------
__device__ __forceinline__ void prep_path(const WPack& p,
                                          unsigned short* __restrict__ wout,
                                          float* __restrict__ bout,
                                          unsigned* __restrict__ hdr) {
    constexpr int cin[9]  = {67, 32, 32,  67, 64, 64,  67, 64, 96};
    constexpr int cout[9] = {32, 32, 64,  64, 64, 128, 64, 96, 128};
    constexpr int sw[9]   = {104, 40, 40, 104, 72, 72, 104, 72, 104};
    constexpr int woff[9] = {0, 3328, 4608, 7168, 13824, 18432, 27648, 34304, 41216};
    constexpr int boff[9] = {0, 32, 64, 128, 192, 256, 384, 448, 544};
    const int L = blockIdx.x - 8;
    const float* w = p.w[L];
    const int ci = cin[L], co = cout[L], s = sw[L];
    unsigned short* dst = wout + woff[L];
    for (int e = threadIdx.x; e < co * s; e += 256) {
        const int n = e / s, k = e % s;
        dst[e] = (k < ci) ? f2bf(w[(size_t)k * co + n]) : (unsigned short)0;
    }
    for (int e = threadIdx.x; e < co; e += 256) bout[boff[L] + e] = p.b[L][e];
    __syncthreads();
    if (threadIdx.x == 0)
        __hip_atomic_fetch_add(&hdr[H_PREP], 1u, __ATOMIC_RELEASE, SCOPE_AGENT);
}

// Poll one group's centroid words until non-poison (lane0), broadcast to wave.
__device__ __forceinline__ void poll_centroid(const float* __restrict__ newxyz,
                                              int g, int lane,
                                              float& ncx, float& ncy, float& ncz) {
    const unsigned* ncw = (const unsigned*)(newxyz + (size_t)g * 3);
    unsigned w0 = 0, w1 = 0, w2 = 0;
    if (lane == 0) {
        int n = 0;
        for (;;) {
            w0 = __hip_atomic_load(&ncw[0], __ATOMIC_RELAXED, SCOPE_AGENT);
            w1 = __hip_atomic_load(&ncw[1], __ATOMIC_RELAXED, SCOPE_AGENT);
            w2 = __hip_atomic_load(&ncw[2], __ATOMIC_RELAXED, SCOPE_AGENT);
            if (w0 != POISON && w1 != POISON && w2 != POISON) break;
            if (++n > SPIN_GUARD) break;                 // watchdog
            if (n < 64) __builtin_amdgcn_s_sleep(8);
            else        __builtin_amdgcn_s_sleep(32);
        }
    }
    ncx = __uint_as_float((unsigned)__builtin_amdgcn_readfirstlane((int)w0));
    ncy = __uint_as_float((unsigned)__builtin_amdgcn_readfirstlane((int)w1));
    ncz = __uint_as_float((unsigned)__builtin_amdgcn_readfirstlane((int)w2));
}

// ---------------------------------------------------------------------------
// Single-radius ball query for one group, one wave.
// ---------------------------------------------------------------------------
template <int NS>
__device__ __forceinline__ void ballq1(const float* __restrict__ base,
                                       float cx, float cy, float cz, float r2,
                                       unsigned short* __restrict__ out, int lane) {
    int cnt = 0, first = 0;
    const u64 lower = (((u64)1) << lane) - 1;
    for (int it = 0; it < 64; ++it) {
        const int j = it * 64 + lane;
        const float* pp = base + j * 3;
        const float dx = pp[0] - cx;
        const float dy = pp[1] - cy;
        const float dz = pp[2] - cz;
        const float d2 = __fadd_rn(__fadd_rn(__fmul_rn(dx, dx), __fmul_rn(dy, dy)),
                                   __fmul_rn(dz, dz));
        const bool in = d2 < r2;
        const u64 m = __ballot(in);
        if (cnt == 0 && m) first = it * 64 + (int)__builtin_ctzll(m);
        const int pos = cnt + (int)__builtin_popcountll(m & lower);
        if (in && pos < NS) out[pos] = (unsigned short)j;
        cnt += (int)__builtin_popcountll(m);
        if (cnt >= NS) break;
    }
    for (int pos = cnt + lane; pos < NS; pos += 64) out[pos] = (unsigned short)first;
}

// ---------------------------------------------------------------------------
// Layer 1, A-fragments DIRECT from global points (no LDS staging, no gather).
// ---------------------------------------------------------------------------
template <int MW, int Cout, int SOUT>
__device__ __forceinline__ void layer1_direct(
    const float* __restrict__ pts,        // points + bb*4096*64
    const float* __restrict__ xyzb,       // xyz + bb*12288
    const unsigned short* __restrict__ idxb,  // LDS, rows for this tile
    float ncx, float ncy, float ncz,
    const unsigned short* __restrict__ Wg, const float* __restrict__ bg,
    unsigned short* __restrict__ dst, int lane, int mslice) {
    constexpr int SW = 104;
    constexpr int MT = MW / 16;
    constexpr int NT = Cout / 16;
    const int ml = lane & 15;
    const int quad = lane >> 4;

    bf16x8 afr[MT][3];
#pragma unroll
    for (int mt = 0; mt < MT; ++mt) {
        const int row = mslice * MW + mt * 16 + ml;
        const int id = idxb[row] & 4095;
        const float* rb = pts + ((size_t)id << 6) + quad * 8;
        const float4* r4 = reinterpret_cast<const float4*>(rb);
        afr[mt][0] = cvt8(r4[0], r4[1]);
        const float4* r4b = reinterpret_cast<const float4*>(rb + 32);
        afr[mt][1] = cvt8(r4b[0], r4b[1]);
        union { bf16x8 v; unsigned short h[8]; } tg;
        tg.v = (bf16x8)(short)0;
        if (quad == 0) {
            const float* pz = xyzb + (size_t)id * 3;
            tg.h[0] = f2bf(pz[0] - ncx);
            tg.h[1] = f2bf(pz[1] - ncy);
            tg.h[2] = f2bf(pz[2] - ncz);
        }
        afr[mt][2] = tg.v;
    }

    f32x4 acc[MT][NT];
#pragma unroll
    for (int mt = 0; mt < MT; ++mt)
#pragma unroll
        for (int nt = 0; nt < NT; ++nt) acc[mt][nt] = (f32x4){0.f, 0.f, 0.f, 0.f};

#pragma unroll
    for (int ks = 0; ks < 3; ++ks) {
        bf16x8 bfr[NT];
#pragma unroll
        for (int nt = 0; nt < NT; ++nt)
            bfr[nt] = *reinterpret_cast<const bf16x8*>(
                Wg + (nt * 16 + ml) * SW + ks * 32 + quad * 8);
#pragma unroll
        for (int mt = 0; mt < MT; ++mt)
#pragma unroll
            for (int nt = 0; nt < NT; ++nt)
                acc[mt][nt] = __builtin_amdgcn_mfma_f32_16x16x32_bf16(
                    afr[mt][ks], bfr[nt], acc[mt][nt], 0, 0, 0);
    }

#pragma unroll
    for (int nt = 0; nt < NT; ++nt) {
        const int col = nt * 16 + ml;
        const float bv = bg[col];
#pragma unroll
        for (int mt = 0; mt < MT; ++mt)
#pragma unroll
            for (int r = 0; r < 4; ++r) {
                const float v = fmaxf(acc[mt][nt][r] + bv, 0.0f);
                dst[(mslice * MW + mt * 16 + quad * 4 + r) * SOUT + col] = f2bf(v);
            }
    }
}

// Middle layer: A from LDS, B from prepped global; relu+store bf16 to LDS.
template <int MW, int Kp, int Cout, int SIN>
__device__ __forceinline__ void layer_mid(const unsigned short* __restrict__ src,
                                          unsigned short* __restrict__ dst,
                                          const unsigned short* __restrict__ Wg,
                                          const float* __restrict__ bg,
                                          int lane, int mslice) {
    constexpr int MT = MW / 16;
    constexpr int NT = Cout / 16;
    constexpr int SOUT = Cout + 8;
    const int ml = lane & 15;
    const int quad = lane >> 4;

    f32x4 acc[MT][NT];
#pragma unroll
    for (int mt = 0; mt < MT; ++mt)
#pragma unroll
        for (int nt = 0; nt < NT; ++nt) acc[mt][nt] = (f32x4){0.f, 0.f, 0.f, 0.f};

#pragma unroll
    for (int ks = 0; ks < Kp; ks += 32) {
        bf16x8 afr[MT], bfr[NT];
#pragma unroll
        for (int mt = 0; mt < MT; ++mt)
            afr[mt] = *reinterpret_cast<const bf16x8*>(
                src + (mslice * MW + mt * 16 + ml) * SIN + ks + quad * 8);
#pragma unroll
        for (int nt = 0; nt < NT; ++nt)
            bfr[nt] = *reinterpret_cast<const bf16x8*>(
                Wg + (nt * 16 + ml) * SIN + ks + quad * 8);
#pragma unroll
        for (int mt = 0; mt < MT; ++mt)
#pragma unroll
            for (int nt = 0; nt < NT; ++nt)
                acc[mt][nt] = __builtin_amdgcn_mfma_f32_16x16x32_bf16(
                    afr[mt], bfr[nt], acc[mt][nt], 0, 0, 0);
    }

#pragma unroll
    for (int nt = 0; nt < NT; ++nt) {
        const int col = nt * 16 + ml;
        const float bv = bg[col];
#pragma unroll
        for (int mt = 0; mt < MT; ++mt)
#pragma unroll
            for (int r = 0; r < 4; ++r) {
                const float v = fmaxf(acc[mt][nt][r] + bv, 0.0f);
                dst[(mslice * MW + mt * 16 + quad * 4 + r) * SOUT + col] = f2bf(v);
            }
    }
}

// Last layer + maxpool. DIRECT: single wave owns the whole group -> write the
// col max straight to global. Else (4-wave tile) atomicMax into LDS Mx.
template <int MW, int Kp, int Cout, int SIN, bool DIRECT>
__device__ __forceinline__ void layer_last(const unsigned short* __restrict__ src,
                                           const unsigned short* __restrict__ Wg,
                                           const float* __restrict__ bg,
                                           float* __restrict__ out,
                                           int lane, int mslice) {
    constexpr int MT = MW / 16;
    constexpr int NT = Cout / 16;
    const int ml = lane & 15;
    const int quad = lane >> 4;

    f32x4 acc[MT][NT];
#pragma unroll
    for (int mt = 0; mt < MT; ++mt)
#pragma unroll
        for (int nt = 0; nt < NT; ++nt) acc[mt][nt] = (f32x4){0.f, 0.f, 0.f, 0.f};

#pragma unroll
    for (int ks = 0; ks < Kp; ks += 32) {
        bf16x8 afr[MT], bfr[NT];
#pragma unroll
        for (int mt = 0; mt < MT; ++mt)
            afr[mt] = *reinterpret_cast<const bf16x8*>(
                src + (mslice * MW + mt * 16 + ml) * SIN + ks + quad * 8);
#pragma unroll
        for (int nt = 0; nt < NT; ++nt)
            bfr[nt] = *reinterpret_cast<const bf16x8*>(
                Wg + (nt * 16 + ml) * SIN + ks + quad * 8);
#pragma unroll
        for (int mt = 0; mt < MT; ++mt)
#pragma unroll
            for (int nt = 0; nt < NT; ++nt)
                acc[mt][nt] = __builtin_amdgcn_mfma_f32_16x16x32_bf16(
                    afr[mt], bfr[nt], acc[mt][nt], 0, 0, 0);
    }

#pragma unroll
    for (int nt = 0; nt < NT; ++nt) {
        const int col = nt * 16 + ml;
        const float bv = bg[col];
        float mx = 0.0f;   // relu floor folds into the max
#pragma unroll
        for (int mt = 0; mt < MT; ++mt)
#pragma unroll
            for (int r = 0; r < 4; ++r) mx = fmaxf(mx, acc[mt][nt][r] + bv);
        mx = fmaxf(mx, __shfl_xor(mx, 16, 64));
        mx = fmaxf(mx, __shfl_xor(mx, 32, 64));
        if (quad == 0) {
            if constexpr (DIRECT) out[col] = mx;
            else atomicMax(reinterpret_cast<int*>(out + col), __float_as_int(mx));
        }
    }
}

// Branch 1/2: 4 groups per item, one wave per group, fully wave-independent.
template <int NS, int C1, int C2, int C3, int CH_OFF>
__device__ __forceinline__ void consume_small(
    unsigned char* smem, const float* __restrict__ xyz,
    const float* __restrict__ points, const float* __restrict__ newxyz,
    const unsigned short* wg1, const unsigned short* wg2, const unsigned short* wg3,
    const float* bg1, const float* bg2, const float* bg3,
    float* __restrict__ outfeat, int gbase, int bb, float r2) {
    constexpr int SB = C1 + 8, SC = C2 + 8;
    unsigned short* Bb = (unsigned short*)smem;        // [4][NS][SB]
    unsigned short* Cb = Bb + 4 * NS * SB;             // [4][NS][SC]
    unsigned short* idxb = Cb + 4 * NS * SC;           // [4][NS]
    const int lane = threadIdx.x & 63;
    const int wave = threadIdx.x >> 6;
    const int g = gbase + wave;
    float ncx, ncy, ncz;
    poll_centroid(newxyz, g, lane, ncx, ncy, ncz);
    const float* xb = xyz + (size_t)bb * 12288;
    unsigned short* idxw = idxb + wave * NS;
    ballq1<NS>(xb, ncx, ncy, ncz, r2, idxw, lane);
    layer1_direct<NS, C1, SB>(points + ((size_t)bb << 18), xb, idxw, ncx, ncy, ncz,
                              wg1, bg1, Bb + wave * NS * SB, lane, 0);
    layer_mid<NS, C1, C2, SB>(Bb + wave * NS * SB, Cb + wave * NS * SC, wg2, bg2,
                              lane, 0);
    layer_last<NS, C2, C3, SC, true>(Cb + wave * NS * SC, wg3, bg3,
                                     outfeat + (size_t)g * 320 + CH_OFF, lane, 0);
}

// Branch 3: one 128-sample group per item, 4 waves (32 rows each).
__device__ __forceinline__ void consume_b3(
    unsigned char* smem, const float* __restrict__ xyz,
    const float* __restrict__ points, const float* __restrict__ newxyz,
    const unsigned short* wg1, const unsigned short* wg2, const unsigned short* wg3,
    const float* bg1, const float* bg2, const float* bg3,
    float* __restrict__ outfeat, int g, int bb) {
    constexpr int SB = 72, SC = 104;
    unsigned short* Bb = (unsigned short*)smem;        // [128][72]
    unsigned short* Cb = Bb + 128 * SB;                // [128][104]
    float* Mx = (float*)(Cb + 128 * SC);               // [128]
    unsigned short* idxb = (unsigned short*)(Mx + 128);// [128]
    float* mail = (float*)(idxb + 128);                // [3] centroid
    const int tid = threadIdx.x;
    const int lane = tid & 63;
    const int wave = tid >> 6;
    const float* xb = xyz + (size_t)bb * 12288;
    float ncx, ncy, ncz;
    if (wave == 0) {
        poll_centroid(newxyz, g, lane, ncx, ncy, ncz);
        if (lane == 0) { mail[0] = ncx; mail[1] = ncy; mail[2] = ncz; }
        ballq1<128>(xb, ncx, ncy, ncz, 0.16f, idxb, lane);
    }
    if (tid >= 128) Mx[tid - 128] = 0.0f;
    __syncthreads();
    if (wave != 0) { ncx = mail[0]; ncy = mail[1]; ncz = mail[2]; }
    layer1_direct<32, 64, SB>(points + ((size_t)bb << 18), xb, idxb, ncx, ncy, ncz,
                              wg1, bg1, Bb, lane, wave);
    layer_mid<32, 64, 96, SB>(Bb, Cb, wg2, bg2, lane, wave);
    layer_last<32, 96, 128, SC, false>(Cb, wg3, bg3, Mx, lane, wave);
    __syncthreads();
    if (tid < 128) outfeat[(size_t)g * 320 + 192 + tid] = Mx[tid];
}

// ---------------------------------------------------------------------------
// Mega kernel (best-measured R7 configuration, locked in). Grid 768 = 256 CU
// x 3 blocks, all co-resident. Blocks 0..7 FPS; 8..16 prep then consume;
// rest consume. Consumers on an FPS CU park until FPS done (static bx%256<8
// + dynamic HW_ID, cap 24). Work dynamically assigned in deadline order:
// 256 chunks x {8 b1, 8 b2, 32 b3} = 12288 items. All waits SPIN_GUARDed.
// ---------------------------------------------------------------------------
__global__ __launch_bounds__(256, 3) void mega_kernel(
    const float* __restrict__ xyz, const float* __restrict__ points, WPack p,
    float* __restrict__ newxyz, float* __restrict__ outfeat,
    unsigned* __restrict__ hdr, unsigned* __restrict__ occ,
    unsigned short* __restrict__ wprep, float* __restrict__ bprep) {
    __shared__ __align__(16) unsigned char smem[49408];
    __shared__ int itemLDS[2];
    const int bx = blockIdx.x;
    if (bx < 8) { fps_path(xyz, newxyz, hdr, occ, smem); return; }
    if (bx < 17) prep_path(p, wprep, bprep, hdr);

    if (threadIdx.x == 0) {
        int n = 0;
        while (__hip_atomic_load(&hdr[H_PLACED], __ATOMIC_RELAXED, SCOPE_AGENT) < 8u &&
               ++n < SPIN_GUARD)
            __builtin_amdgcn_s_sleep(2);
        (void)__hip_atomic_load(&hdr[H_PLACED], __ATOMIC_ACQUIRE, SCOPE_AGENT);
        bool doze = (bx >= 17) && ((bx & 255) < 8);
        if (!doze &&
            __hip_atomic_load(&occ[cu_key()], __ATOMIC_RELAXED, SCOPE_AGENT)) {
            const unsigned prev = __hip_atomic_fetch_add(&hdr[H_SLEEP], 1u,
                                                         __ATOMIC_RELAXED, SCOPE_AGENT);
            doze = (prev < 24u);
        }
        n = 0;
        if (doze)
            while (__hip_atomic_load(&hdr[H_FDONE], __ATOMIC_RELAXED, SCOPE_AGENT) < 8u &&
                   ++n < SPIN_GUARD)
                __builtin_amdgcn_s_sleep(127);
        n = 0;
        while (__hip_atomic_load(&hdr[H_PREP], __ATOMIC_RELAXED, SCOPE_AGENT) < 9u &&
               ++n < SPIN_GUARD)
            __builtin_amdgcn_s_sleep(8);
        (void)__hip_atomic_load(&hdr[H_PREP], __ATOMIC_ACQUIRE, SCOPE_AGENT);
    }

    for (int slot = 0;; slot ^= 1) {
        if (threadIdx.x == 0)
            itemLDS[slot] = (int)__hip_atomic_fetch_add(&hdr[H_ITEM], 1u,
                                                        __ATOMIC_RELAXED, SCOPE_AGENT);
        __syncthreads();   // publishes item; doubles as inter-item LDS barrier
        const int item = itemLDS[slot];
        if (item >= 12288) break;

        const int chunk = item / 48;
        const int r = item - chunk * 48;
        int bb, br, soff = 0;
        if (r < 8)       { br = 0; bb = r; }
        else if (r < 16) { br = 1; bb = r - 8; }
        else             { br = 2; bb = (r - 16) & 7; soff = (r - 16) >> 3; }
        const int gbase = bb * 1024 + chunk * 4;
        if (br == 0)
            consume_small<16, 32, 32, 64, 0>(smem, xyz, points, newxyz,
                wprep + 0, wprep + 3328, wprep + 4608,
                bprep + 0, bprep + 32, bprep + 64, outfeat, gbase, bb, 0.01f);
        else if (br == 1)
            consume_small<32, 64, 64, 128, 64>(smem, xyz, points, newxyz,
                wprep + 7168, wprep + 13824, wprep + 18432,
                bprep + 128, bprep + 192, bprep + 256, outfeat, gbase, bb, 0.04f);
        else
            consume_b3(smem, xyz, points, newxyz,
                wprep + 27648, wprep + 34304, wprep + 41216,
                bprep + 384, bprep + 448, bprep + 544, outfeat, gbase + soff, bb);
    }
}

// ---------------------------------------------------------------------------
extern "C" void kernel_launch(void* const* d_in, const int* in_sizes, int n_in,
                              void* d_out, int out_size, void* d_ws, size_t ws_size,
                              hipStream_t stream) {
    (void)in_sizes; (void)n_in; (void)out_size; (void)ws_size;
    const float* xyz = (const float*)d_in[0];
    const float* points = (const float*)d_in[1];
    WPack pack;
    int p = 2;
    for (int L = 0; L < 9; ++L) {
        pack.w[L] = (const float*)d_in[p++];
        pack.b[L] = (const float*)d_in[p++];
    }
    float* newxyz = (float*)d_out;                  // 8*1024*3
    float* outfeat = (float*)d_out + 8 * 1024 * 3;  // 8*1024*320

    // ws layout: [0,256) hdr, [256,8448) occupancy map (2048 u32),
    // [8448, +109056) prepped bf16 weights, then f32 biases.
    unsigned* hdr = (unsigned*)d_ws;
    unsigned* occ = (unsigned*)((char*)d_ws + 256);
    unsigned short* wprep = (unsigned short*)((char*)d_ws + 8448);
    float* bprep = (float*)((char*)d_ws + 8448 + 109056);

    (void)hipMemsetAsync(d_ws, 0, 8448, stream);              // counters + CU map
    (void)hipMemsetAsync(newxyz, 0xFF, 8 * 1024 * 3 * 4, stream);  // poison centroids
    mega_kernel<<<dim3(768), dim3(256), 0, stream>>>(
        xyz, points, pack, newxyz, outfeat, hdr, occ, wprep, bprep);
}